// Round 7
// baseline (202.273 us; speedup 1.0000x reference)
//
#include <hip/hip_runtime.h>
#include <stdint.h>

typedef unsigned int u32;
typedef unsigned short u16;
typedef float f32x4 __attribute__((ext_vector_type(4)));
typedef __fp16 h16x2 __attribute__((ext_vector_type(2)));   // cvt_pkrtz native type
typedef _Float16 f16x8 __attribute__((ext_vector_type(8)));
typedef float f4u __attribute__((ext_vector_type(4), aligned(4)));  // 4B-aligned vec load

#define NB   8
#define CIN  256
#define HH   64
#define WW   64
#define HW   4096
#define COUT 256
#define NPX  128   // pixels per block (2 output rows)
#define BSTR 264   // u16 per Bs row (256 + 8 pad; 528B = 33*16B)

__device__ __forceinline__ u32 pkh(float lo, float hi) {
  h16x2 h = __builtin_amdgcn_cvt_pkrtz(lo, hi);   // v_cvt_pkrtz_f16_f32, 1 instr
  return __builtin_bit_cast(u32, h);
}
union HU { u32 u; h16x2 h; };

// ---- prep_all: blocks 0..2047 transpose x -> xT (fp16 NHWC); rest weights ----
// W2f frag layout: frag = (kk*8+cc)*16 + tile; element: lane*8+j ;
// co = (tile>>2)*64 + (tile&3)*16 + (lane&15); c = cc*32 + (lane>>4)*8 + j.
__global__ __launch_bounds__(256) void prep_all(const float* __restrict__ x,
                                                const float* __restrict__ wgt,
                                                u32* __restrict__ xT,
                                                u32* __restrict__ W2f32) {
  int b = blockIdx.x;
  int t = threadIdx.x;
  if (b < 2048) {
    __shared__ __align__(16) u32 tile[16][132];
    int n = b >> 8, hw0 = (b & 255) << 4;
    int hwq = (t & 3) << 2;          // 0,4,8,12
    int cp0 = t >> 2;                // 0..63
    const float* xb = x + (size_t)n * CIN * HW + hw0 + hwq;
#pragma unroll
    for (int it = 0; it < 2; ++it) {
      int cp = (it << 6) + cp0;      // 0..127
      int c = cp << 1;
      f4u v0 = *(const f4u*)(xb + (size_t)c * HW);
      f4u v1 = *(const f4u*)(xb + (size_t)(c + 1) * HW);
      tile[hwq + 0][cp] = pkh(v0.x, v1.x);
      tile[hwq + 1][cp] = pkh(v0.y, v1.y);
      tile[hwq + 2][cp] = pkh(v0.z, v1.z);
      tile[hwq + 3][cp] = pkh(v0.w, v1.w);
    }
    __syncthreads();
    u32* outp = xT + ((size_t)(n * HW + hw0)) * 128;
    int cq = t & 31, hb = t >> 5;    // cq: uint4 col 0..31, hb: row 0..7
#pragma unroll
    for (int it = 0; it < 2; ++it) {
      int hwl = (it << 3) + hb;
      uint4 v = *(const uint4*)&tile[hwl][cq << 2];   // ds_read_b128, 16B-aligned
      *(uint4*)(outp + (size_t)hwl * 128 + (cq << 2)) = v;  // 512B/half-wave
    }
  } else {
    // weights: thread = (co, c-pair); reads 18 consecutive floats
    int tt = (b - 2048) * 256 + t;   // 32768 total
    int cp = tt & 127, co = tt >> 7;
    int c = cp << 1;
    const float* p = wgt + ((size_t)co * CIN + c) * 9;
    f4u q0 = *(const f4u*)(p + 0);
    f4u q1 = *(const f4u*)(p + 4);
    f4u q2 = *(const f4u*)(p + 8);
    f4u q3 = *(const f4u*)(p + 12);
    float e16 = p[16], e17 = p[17];
    float a0[9], a1[9];
    a0[0]=q0.x; a0[1]=q0.y; a0[2]=q0.z; a0[3]=q0.w;
    a0[4]=q1.x; a0[5]=q1.y; a0[6]=q1.z; a0[7]=q1.w; a0[8]=q2.x;
    a1[0]=q2.y; a1[1]=q2.z; a1[2]=q2.w;
    a1[3]=q3.x; a1[4]=q3.y; a1[5]=q3.z; a1[6]=q3.w; a1[7]=e16; a1[8]=e17;
    int cc = c >> 5;
    int j = (c >> 1) & 3;
    int lane = (co & 15) | (((c >> 3) & 3) << 4);
    int tile_ = ((co >> 6) << 2) | ((co >> 4) & 3);
#pragma unroll
    for (int kk = 0; kk < 9; ++kk) {
      int frag = (kk * 8 + cc) * 16 + tile_;
      W2f32[(size_t)frag * 256 + lane * 4 + j] = pkh(a0[kk], a1[kk]);
    }
  }
}

// ---- main: 256 blocks x 1024 threads; block = 256 Cout x 128 px (2 rows) ----
// r7 = r5 producer/consumer structure with ONE change: consumer tiling
// 32Cout x 128px -> 64Cout x 64px (4 coT x 2 pxh). B-tile LDS redundancy
// 8x -> 4x (reads 512->256KB/tap); af frags now L1-shared by the pxh pair.
// Producers (waves 8..15) byte-identical to r5: 8 tasks, depth-1 prefetch,
// named SSA only (r4/r6 spill lesson; tripwire = FETCH ~16MB / WRITE ~38MB).
__global__ __launch_bounds__(1024, 4) void dcn_main(
    const float* __restrict__ offset, const float* __restrict__ mask,
    const float* __restrict__ bias, const u16* __restrict__ xT,
    const u16* __restrict__ W2f, float* __restrict__ out) {
  __shared__ __align__(16) u16 Bs[2][NPX * BSTR];  // 2 x 67.6 KB
  __shared__ __align__(8)  uint2 swl[1152];        // (kk,p): 4 corner wts, fp16 pairs
  __shared__ __align__(8)  ushort4 sol[1152];      // (kk,p): 4 corner position indices

  int bid = blockIdx.x;      // 256 blocks = 1/CU
  int n = bid & 7;           // XCD swizzle: XCD k serves n==k -> 2MB xT slice in L2
  int hp = bid >> 3;         // ho-pair 0..31
  int t = threadIdx.x;
  int lane = t & 63;
  int w = t >> 6;            // wave 0..15
  bool prod = (w >= 8);

  // 1) sample precompute: 9 taps x 128 px
  for (int i = t; i < 1152; i += 1024) {
    int kk = i >> 7, p = i & 127;
    int ky = kk / 3, kx = kk - ky * 3;
    int sp = (hp << 7) + p;             // = ho*64 + (p&63)
    int ho = (hp << 1) + (p >> 6);
    float dy = offset[(((size_t)n * 18 + kk * 2 + 0) << 12) + sp];
    float dx = offset[(((size_t)n * 18 + kk * 2 + 1) << 12) + sp];
    float m  = mask  [(((size_t)n * 9  + kk) << 12) + sp];
    float ys = (float)(ky + ho - 1) + dy;
    float xs = (float)(kx + (p & 63) - 1) + dx;
    float y0f = floorf(ys), x0f = floorf(xs);
    float fy = ys - y0f, fx = xs - x0f;
    int y0 = (int)y0f, x0 = (int)x0f;
    int y1 = y0 + 1, x1 = x0 + 1;
    float vy0 = (y0 >= 0 && y0 < HH) ? 1.f : 0.f;
    float vy1 = (y1 >= 0 && y1 < HH) ? 1.f : 0.f;
    float vx0 = (x0 >= 0 && x0 < WW) ? 1.f : 0.f;
    float vx1 = (x1 >= 0 && x1 < WW) ? 1.f : 0.f;
    float w0 = (1.f - fy) * (1.f - fx) * m * vy0 * vx0;
    float w1 = (1.f - fy) * fx * m * vy0 * vx1;
    float w2 = fy * (1.f - fx) * m * vy1 * vx0;
    float w3 = fy * fx * m * vy1 * vx1;
    int iy0 = min(max(y0, 0), HH - 1), iy1 = min(max(y1, 0), HH - 1);
    int ix0 = min(max(x0, 0), WW - 1), ix1 = min(max(x1, 0), WW - 1);
    ushort4 pv;
    pv.x = (u16)((iy0 << 6) + ix0);
    pv.y = (u16)((iy0 << 6) + ix1);
    pv.z = (u16)((iy1 << 6) + ix0);
    pv.w = (u16)((iy1 << 6) + ix1);
    swl[i] = make_uint2(pkh(w0, w1), pkh(w2, w3));
    sol[i] = pv;
  }
  __syncthreads();

  f32x4 acc[4][4];
#pragma unroll
  for (int a = 0; a < 4; ++a)
#pragma unroll
    for (int b2 = 0; b2 < 4; ++b2) acc[a][b2] = {0.f, 0.f, 0.f, 0.f};

  const char* xTn = (const char*)xT + ((size_t)n * HW << 9);
  int ml = lane & 15, q = lane >> 4;
  int hw32 = t >> 5;     // half-wave id 0..31 (prologue build)
  int l32 = t & 31;
  int coT = w & 3, pxh = (w >> 2) & 1;               // consumer: 64Cout x 64px
  int tile0 = coT << 2;
  int rbase = pxh << 6;                               // px row base 0 or 64
  const char* bch = xTn + (l32 << 4);
  // producer indexing: 512 threads cover 128 px x 32 chunks, 8 tasks each
  int tp = t - 512;              // 0..511 (producers only)
  int ch = tp & 31;              // 16B channel chunk
  int ph = tp >> 5;              // 0..15; px = s*16 + ph
  const char* bchp = xTn + (ch << 4);

// accumulate one register-resident corner (8 v_fma_mix_f32)
#define CMB(G, WT) do {                                                \
    float wt = (WT);                                                   \
    HU h0, h1, h2, h3;                                                 \
    h0.u = (G).x; h1.u = (G).y; h2.u = (G).z; h3.u = (G).w;            \
    s0 = __builtin_fmaf((float)h0.h.x, wt, s0);                        \
    s1 = __builtin_fmaf((float)h0.h.y, wt, s1);                        \
    s2 = __builtin_fmaf((float)h1.h.x, wt, s2);                        \
    s3 = __builtin_fmaf((float)h1.h.y, wt, s3);                        \
    s4 = __builtin_fmaf((float)h2.h.x, wt, s4);                        \
    s5 = __builtin_fmaf((float)h2.h.y, wt, s5);                        \
    s6 = __builtin_fmaf((float)h3.h.x, wt, s6);                        \
    s7 = __builtin_fmaf((float)h3.h.y, wt, s7);                        \
  } while (0)

  // monolithic build for the prologue (tap 0 into buf 0, all 16 waves)
  auto build0 = [&](int g) {
    int px = (g << 5) + hw32;
    uint2 wu = swl[px];
    ushort4 pv = sol[px];
    HU ha, hb; ha.u = wu.x; hb.u = wu.y;
    uint4 G0 = *(const uint4*)(bch + ((int)pv.x << 9));
    uint4 G1 = *(const uint4*)(bch + ((int)pv.y << 9));
    uint4 G2 = *(const uint4*)(bch + ((int)pv.z << 9));
    uint4 G3 = *(const uint4*)(bch + ((int)pv.w << 9));
    float s0=0.f,s1=0.f,s2=0.f,s3=0.f,s4=0.f,s5=0.f,s6=0.f,s7=0.f;
    CMB(G0, (float)ha.h.x);
    CMB(G1, (float)ha.h.y);
    CMB(G2, (float)hb.h.x);
    CMB(G3, (float)hb.h.y);
    uint4 pkd;
    pkd.x = pkh(s0, s1); pkd.y = pkh(s2, s3);
    pkd.z = pkh(s4, s5); pkd.w = pkh(s6, s7);
    *(uint4*)((char*)&Bs[0][0] + px * (BSTR * 2) + (l32 << 4)) = pkd;
  };

  auto af_load = [&](int fidx, int mt) {
    return *(const f16x8*)(W2f + (((size_t)((fidx << 4) + tile0 + mt)) << 9) +
                           (lane << 3));
  };
  auto bf_load = [&](const char* Br, int nt, int cc) {
    return *(const f16x8*)(Br + ((rbase + (nt << 4) + ml)) * (BSTR * 2) +
                           (cc << 6) + (q << 4));
  };

#pragma unroll
  for (int g = 0; g < 4; ++g) build0(g);

  // consumer: A-fragments for tap 0 / cc 0 (4 m-tiles), prefetched, named
  f16x8 a0, a1, a2, a3;
  if (!prod) {
    a0 = af_load(0, 0); a1 = af_load(0, 1);
    a2 = af_load(0, 2); a3 = af_load(0, 3);
  }
  __syncthreads();

#pragma unroll 1
  for (int kk = 0; kk < 9; ++kk) {
    if (prod) {
      // ---- producer: build tap kk+1 into the other buffer (r5 verbatim) ----
      if (kk < 8) {
        char* Bw = (char*)&Bs[(kk & 1) ^ 1][0];
        int base = (kk + 1) << 7;
        uint2 wA = swl[base + ph];
        ushort4 pvA = sol[base + ph];
        uint4 A0 = *(const uint4*)(bchp + ((int)pvA.x << 9));
        uint4 A1 = *(const uint4*)(bchp + ((int)pvA.y << 9));
        uint4 A2 = *(const uint4*)(bchp + ((int)pvA.z << 9));
        uint4 A3 = *(const uint4*)(bchp + ((int)pvA.w << 9));
#pragma unroll
        for (int s = 0; s < 8; ++s) {
          uint4 B0, B1, B2, B3; uint2 wB;
          if (s < 7) {   // depth-1 prefetch: issue next px's gathers first
            ushort4 pv = sol[base + ((s + 1) << 4) + ph];
            wB = swl[base + ((s + 1) << 4) + ph];
            B0 = *(const uint4*)(bchp + ((int)pv.x << 9));
            B1 = *(const uint4*)(bchp + ((int)pv.y << 9));
            B2 = *(const uint4*)(bchp + ((int)pv.z << 9));
            B3 = *(const uint4*)(bchp + ((int)pv.w << 9));
          }
          {
            HU ha, hb; ha.u = wA.x; hb.u = wA.y;
            float s0=0.f,s1=0.f,s2=0.f,s3=0.f,s4=0.f,s5=0.f,s6=0.f,s7=0.f;
            CMB(A0, (float)ha.h.x);
            CMB(A1, (float)ha.h.y);
            CMB(A2, (float)hb.h.x);
            CMB(A3, (float)hb.h.y);
            uint4 pkd;
            pkd.x = pkh(s0, s1); pkd.y = pkh(s2, s3);
            pkd.z = pkh(s4, s5); pkd.w = pkh(s6, s7);
            *(uint4*)(Bw + ((s << 4) + ph) * (BSTR * 2) + (ch << 4)) = pkd;
          }
          wA = wB; A0 = B0; A1 = B1; A2 = B2; A3 = B3;  // SSA rotate (unrolled)
        }
      }
    } else {
      // ---- consumer: 64Cout x 64px over Bs[kk&1]; af dbuf one cc ahead ----
      const char* Br = (const char*)&Bs[kk & 1][0];
      int fbase = kk << 3;
#pragma unroll
      for (int cc = 0; cc < 8; ++cc) {
        f16x8 b0 = bf_load(Br, 0, cc);
        f16x8 b1 = bf_load(Br, 1, cc);
        f16x8 b2 = bf_load(Br, 2, cc);
        f16x8 b3 = bf_load(Br, 3, cc);
        f16x8 n0, n1, n2, n3;
        if (cc < 7) {
          n0 = af_load(fbase + cc + 1, 0); n1 = af_load(fbase + cc + 1, 1);
          n2 = af_load(fbase + cc + 1, 2); n3 = af_load(fbase + cc + 1, 3);
        } else if (kk < 8) {
          n0 = af_load(fbase + 8, 0); n1 = af_load(fbase + 8, 1);
          n2 = af_load(fbase + 8, 2); n3 = af_load(fbase + 8, 3);
        }
        __builtin_amdgcn_s_setprio(1);
        acc[0][0] = __builtin_amdgcn_mfma_f32_16x16x32_f16(a0, b0, acc[0][0], 0, 0, 0);
        acc[0][1] = __builtin_amdgcn_mfma_f32_16x16x32_f16(a0, b1, acc[0][1], 0, 0, 0);
        acc[0][2] = __builtin_amdgcn_mfma_f32_16x16x32_f16(a0, b2, acc[0][2], 0, 0, 0);
        acc[0][3] = __builtin_amdgcn_mfma_f32_16x16x32_f16(a0, b3, acc[0][3], 0, 0, 0);
        acc[1][0] = __builtin_amdgcn_mfma_f32_16x16x32_f16(a1, b0, acc[1][0], 0, 0, 0);
        acc[1][1] = __builtin_amdgcn_mfma_f32_16x16x32_f16(a1, b1, acc[1][1], 0, 0, 0);
        acc[1][2] = __builtin_amdgcn_mfma_f32_16x16x32_f16(a1, b2, acc[1][2], 0, 0, 0);
        acc[1][3] = __builtin_amdgcn_mfma_f32_16x16x32_f16(a1, b3, acc[1][3], 0, 0, 0);
        acc[2][0] = __builtin_amdgcn_mfma_f32_16x16x32_f16(a2, b0, acc[2][0], 0, 0, 0);
        acc[2][1] = __builtin_amdgcn_mfma_f32_16x16x32_f16(a2, b1, acc[2][1], 0, 0, 0);
        acc[2][2] = __builtin_amdgcn_mfma_f32_16x16x32_f16(a2, b2, acc[2][2], 0, 0, 0);
        acc[2][3] = __builtin_amdgcn_mfma_f32_16x16x32_f16(a2, b3, acc[2][3], 0, 0, 0);
        acc[3][0] = __builtin_amdgcn_mfma_f32_16x16x32_f16(a3, b0, acc[3][0], 0, 0, 0);
        acc[3][1] = __builtin_amdgcn_mfma_f32_16x16x32_f16(a3, b1, acc[3][1], 0, 0, 0);
        acc[3][2] = __builtin_amdgcn_mfma_f32_16x16x32_f16(a3, b2, acc[3][2], 0, 0, 0);
        acc[3][3] = __builtin_amdgcn_mfma_f32_16x16x32_f16(a3, b3, acc[3][3], 0, 0, 0);
        __builtin_amdgcn_s_setprio(0);
        a0 = n0; a1 = n1; a2 = n2; a3 = n3;   // SSA rotate (unrolled)
      }
    }
    __syncthreads();   // producers done writing Bs[cur^1]; consumers done reading Bs[cur]
  }

  // epilogue: consumers hold complete sums -- direct store, no LDS reduce
  if (!prod) {
    // D layout: row = q*4+r (Cout), col = ml (px); m91-verified
    size_t ob = (size_t)n * COUT * HW + ((size_t)hp << 7);
#pragma unroll
    for (int mt = 0; mt < 4; ++mt) {
      int co0 = (coT << 6) + (mt << 4) + (q << 2);
      f4u bv = *(const f4u*)&bias[co0];
#pragma unroll
      for (int nt = 0; nt < 4; ++nt) {
        int px = rbase + (nt << 4) + ml;
#pragma unroll
        for (int r = 0; r < 4; ++r)
          out[ob + (size_t)(co0 + r) * HW + px] = acc[mt][nt][r] + bv[r];
      }
    }
  }
}

extern "C" void kernel_launch(void* const* d_in, const int* in_sizes, int n_in,
                              void* d_out, int out_size, void* d_ws, size_t ws_size,
                              hipStream_t stream) {
  const float* x      = (const float*)d_in[0];
  const float* offset = (const float*)d_in[1];
  const float* mask   = (const float*)d_in[2];
  const float* weight = (const float*)d_in[3];
  const float* bias   = (const float*)d_in[4];
  float* out = (float*)d_out;

  u16* xT  = (u16*)d_ws;                                      // 16 MB fp16
  u16* W2f = (u16*)((char*)d_ws + (size_t)NB * HW * CIN * 2); // +1.18 MB fp16

  prep_all<<<2176, 256, 0, stream>>>(x, weight, (u32*)xT, (u32*)W2f);
  dcn_main<<<256, 1024, 0, stream>>>(offset, mask, bias, xT, W2f, out);
}

// Round 8
// 149.603 us; speedup vs baseline: 1.3521x; 1.3521x over previous
//
#include <hip/hip_runtime.h>
#include <stdint.h>

typedef unsigned int u32;
typedef unsigned short u16;
typedef float f32x4 __attribute__((ext_vector_type(4)));
typedef __fp16 h16x2 __attribute__((ext_vector_type(2)));   // cvt_pkrtz native type
typedef _Float16 f16x8 __attribute__((ext_vector_type(8)));
typedef float f4u __attribute__((ext_vector_type(4), aligned(4)));  // 4B-aligned vec load

#define NB   8
#define CIN  256
#define HH   64
#define WW   64
#define HW   4096
#define COUT 256
#define NPX  128   // pixels per block (2 output rows)
#define BSTR 264   // u16 per Bs row (256 + 8 pad; 528B = 33*16B)

__device__ __forceinline__ u32 pkh(float lo, float hi) {
  h16x2 h = __builtin_amdgcn_cvt_pkrtz(lo, hi);   // v_cvt_pkrtz_f16_f32, 1 instr
  return __builtin_bit_cast(u32, h);
}
union HU { u32 u; h16x2 h; };

// ---- prep_all: blocks 0..2047 transpose x -> xT (fp16 NHWC); rest weights ----
// W2f frag layout: frag = (kk*8+cc)*16 + tile; element: lane*8+j ;
// co = (tile>>2)*64 + (tile&3)*16 + (lane&15); c = cc*32 + (lane>>4)*8 + j.
__global__ __launch_bounds__(256) void prep_all(const float* __restrict__ x,
                                                const float* __restrict__ wgt,
                                                u32* __restrict__ xT,
                                                u32* __restrict__ W2f32) {
  int b = blockIdx.x;
  int t = threadIdx.x;
  if (b < 2048) {
    __shared__ __align__(16) u32 tile[16][132];
    int n = b >> 8, hw0 = (b & 255) << 4;
    int hwq = (t & 3) << 2;          // 0,4,8,12
    int cp0 = t >> 2;                // 0..63
    const float* xb = x + (size_t)n * CIN * HW + hw0 + hwq;
#pragma unroll
    for (int it = 0; it < 2; ++it) {
      int cp = (it << 6) + cp0;      // 0..127
      int c = cp << 1;
      f4u v0 = *(const f4u*)(xb + (size_t)c * HW);
      f4u v1 = *(const f4u*)(xb + (size_t)(c + 1) * HW);
      tile[hwq + 0][cp] = pkh(v0.x, v1.x);
      tile[hwq + 1][cp] = pkh(v0.y, v1.y);
      tile[hwq + 2][cp] = pkh(v0.z, v1.z);
      tile[hwq + 3][cp] = pkh(v0.w, v1.w);
    }
    __syncthreads();
    u32* outp = xT + ((size_t)(n * HW + hw0)) * 128;
    int cq = t & 31, hb = t >> 5;    // cq: uint4 col 0..31, hb: row 0..7
#pragma unroll
    for (int it = 0; it < 2; ++it) {
      int hwl = (it << 3) + hb;
      uint4 v = *(const uint4*)&tile[hwl][cq << 2];   // ds_read_b128, 16B-aligned
      *(uint4*)(outp + (size_t)hwl * 128 + (cq << 2)) = v;  // 512B/half-wave
    }
  } else {
    // weights: thread = (co, c-pair); reads 18 consecutive floats
    int tt = (b - 2048) * 256 + t;   // 32768 total
    int cp = tt & 127, co = tt >> 7;
    int c = cp << 1;
    const float* p = wgt + ((size_t)co * CIN + c) * 9;
    f4u q0 = *(const f4u*)(p + 0);
    f4u q1 = *(const f4u*)(p + 4);
    f4u q2 = *(const f4u*)(p + 8);
    f4u q3 = *(const f4u*)(p + 12);
    float e16 = p[16], e17 = p[17];
    float a0[9], a1[9];
    a0[0]=q0.x; a0[1]=q0.y; a0[2]=q0.z; a0[3]=q0.w;
    a0[4]=q1.x; a0[5]=q1.y; a0[6]=q1.z; a0[7]=q1.w; a0[8]=q2.x;
    a1[0]=q2.y; a1[1]=q2.z; a1[2]=q2.w;
    a1[3]=q3.x; a1[4]=q3.y; a1[5]=q3.z; a1[6]=q3.w; a1[7]=e16; a1[8]=e17;
    int cc = c >> 5;
    int j = (c >> 1) & 3;
    int lane = (co & 15) | (((c >> 3) & 3) << 4);
    int tile_ = ((co >> 6) << 2) | ((co >> 4) & 3);
#pragma unroll
    for (int kk = 0; kk < 9; ++kk) {
      int frag = (kk * 8 + cc) * 16 + tile_;
      W2f32[(size_t)frag * 256 + lane * 4 + j] = pkh(a0[kk], a1[kk]);
    }
  }
}

// ---- main: 256 blocks x 768 threads (12 waves = 3/SIMD -> ~168 reg budget) ----
// r8 synthesis: unified-RF arithmetic says r7's 64Cout x 64px consumer (~142
// regs: 64 acc AGPR + af-dbuf + bf) needs the 3-wave/SIMD budget, not 4.
// Waves 0..7 = r7's consumer verbatim (passed; halves LDS B-traffic to
// 256KB/tap). Waves 8..11 = r5's depth-1 producer verbatim (passed), 16
// tasks each (ph 0..7, px = s*8+ph, s 0..15). NO bb/nn B-dbuf (r6's spill).
// Spill tripwire: FETCH ~16MB / WRITE ~38MB, else reject.
__global__ __launch_bounds__(768, 3) void dcn_main(
    const float* __restrict__ offset, const float* __restrict__ mask,
    const float* __restrict__ bias, const u16* __restrict__ xT,
    const u16* __restrict__ W2f, float* __restrict__ out) {
  __shared__ __align__(16) u16 Bs[2][NPX * BSTR];  // 2 x 67.6 KB
  __shared__ __align__(8)  uint2 swl[1152];        // (kk,p): 4 corner wts, fp16 pairs
  __shared__ __align__(8)  ushort4 sol[1152];      // (kk,p): 4 corner position indices

  int bid = blockIdx.x;      // 256 blocks = 1/CU
  int n = bid & 7;           // XCD swizzle: XCD k serves n==k -> 2MB xT slice in L2
  int hp = bid >> 3;         // ho-pair 0..31
  int t = threadIdx.x;
  int lane = t & 63;
  int w = t >> 6;            // wave 0..11
  bool prod = (w >= 8);

  // 1) sample precompute: 9 taps x 128 px
  for (int i = t; i < 1152; i += 768) {
    int kk = i >> 7, p = i & 127;
    int ky = kk / 3, kx = kk - ky * 3;
    int sp = (hp << 7) + p;             // = ho*64 + (p&63)
    int ho = (hp << 1) + (p >> 6);
    float dy = offset[(((size_t)n * 18 + kk * 2 + 0) << 12) + sp];
    float dx = offset[(((size_t)n * 18 + kk * 2 + 1) << 12) + sp];
    float m  = mask  [(((size_t)n * 9  + kk) << 12) + sp];
    float ys = (float)(ky + ho - 1) + dy;
    float xs = (float)(kx + (p & 63) - 1) + dx;
    float y0f = floorf(ys), x0f = floorf(xs);
    float fy = ys - y0f, fx = xs - x0f;
    int y0 = (int)y0f, x0 = (int)x0f;
    int y1 = y0 + 1, x1 = x0 + 1;
    float vy0 = (y0 >= 0 && y0 < HH) ? 1.f : 0.f;
    float vy1 = (y1 >= 0 && y1 < HH) ? 1.f : 0.f;
    float vx0 = (x0 >= 0 && x0 < WW) ? 1.f : 0.f;
    float vx1 = (x1 >= 0 && x1 < WW) ? 1.f : 0.f;
    float w0 = (1.f - fy) * (1.f - fx) * m * vy0 * vx0;
    float w1 = (1.f - fy) * fx * m * vy0 * vx1;
    float w2 = fy * (1.f - fx) * m * vy1 * vx0;
    float w3 = fy * fx * m * vy1 * vx1;
    int iy0 = min(max(y0, 0), HH - 1), iy1 = min(max(y1, 0), HH - 1);
    int ix0 = min(max(x0, 0), WW - 1), ix1 = min(max(x1, 0), WW - 1);
    ushort4 pv;
    pv.x = (u16)((iy0 << 6) + ix0);
    pv.y = (u16)((iy0 << 6) + ix1);
    pv.z = (u16)((iy1 << 6) + ix0);
    pv.w = (u16)((iy1 << 6) + ix1);
    swl[i] = make_uint2(pkh(w0, w1), pkh(w2, w3));
    sol[i] = pv;
  }
  __syncthreads();

  f32x4 acc[4][4];
#pragma unroll
  for (int a = 0; a < 4; ++a)
#pragma unroll
    for (int b2 = 0; b2 < 4; ++b2) acc[a][b2] = {0.f, 0.f, 0.f, 0.f};

  const char* xTn = (const char*)xT + ((size_t)n * HW << 9);
  int ml = lane & 15, q = lane >> 4;
  int coT = w & 3, pxh = (w >> 2) & 1;               // consumer: 64Cout x 64px
  int tile0 = coT << 2;
  int rbase = pxh << 6;                               // px row base 0 or 64
  // producer indexing: 256 threads cover 128 px x 32 chunks, 16 tasks each
  int tp = t - 512;              // 0..255 (producers only)
  int ch = tp & 31;              // 16B channel chunk
  int ph = tp >> 5;              // 0..7; px = s*8 + ph
  const char* bchp = xTn + (ch << 4);

// accumulate one register-resident corner (8 v_fma_mix_f32)
#define CMB(G, WT) do {                                                \
    float wt = (WT);                                                   \
    HU h0, h1, h2, h3;                                                 \
    h0.u = (G).x; h1.u = (G).y; h2.u = (G).z; h3.u = (G).w;            \
    s0 = __builtin_fmaf((float)h0.h.x, wt, s0);                        \
    s1 = __builtin_fmaf((float)h0.h.y, wt, s1);                        \
    s2 = __builtin_fmaf((float)h1.h.x, wt, s2);                        \
    s3 = __builtin_fmaf((float)h1.h.y, wt, s3);                        \
    s4 = __builtin_fmaf((float)h2.h.x, wt, s4);                        \
    s5 = __builtin_fmaf((float)h2.h.y, wt, s5);                        \
    s6 = __builtin_fmaf((float)h3.h.x, wt, s6);                        \
    s7 = __builtin_fmaf((float)h3.h.y, wt, s7);                        \
  } while (0)

  auto af_load = [&](int fidx, int mt) {
    return *(const f16x8*)(W2f + (((size_t)((fidx << 4) + tile0 + mt)) << 9) +
                           (lane << 3));
  };
  auto bf_load = [&](const char* Br, int nt, int cc) {
    return *(const f16x8*)(Br + ((rbase + (nt << 4) + ml)) * (BSTR * 2) +
                           (cc << 6) + (q << 4));
  };

  // prologue: build tap 0 into buf 0 -- flat task loop over all 12 waves
  for (int i = t; i < 4096; i += 768) {
    int px = i >> 5, cch = i & 31;
    const char* bc = xTn + (cch << 4);
    uint2 wu = swl[px];
    ushort4 pv = sol[px];
    HU ha, hb; ha.u = wu.x; hb.u = wu.y;
    uint4 G0 = *(const uint4*)(bc + ((int)pv.x << 9));
    uint4 G1 = *(const uint4*)(bc + ((int)pv.y << 9));
    uint4 G2 = *(const uint4*)(bc + ((int)pv.z << 9));
    uint4 G3 = *(const uint4*)(bc + ((int)pv.w << 9));
    float s0=0.f,s1=0.f,s2=0.f,s3=0.f,s4=0.f,s5=0.f,s6=0.f,s7=0.f;
    CMB(G0, (float)ha.h.x);
    CMB(G1, (float)ha.h.y);
    CMB(G2, (float)hb.h.x);
    CMB(G3, (float)hb.h.y);
    uint4 pkd;
    pkd.x = pkh(s0, s1); pkd.y = pkh(s2, s3);
    pkd.z = pkh(s4, s5); pkd.w = pkh(s6, s7);
    *(uint4*)((char*)&Bs[0][0] + px * (BSTR * 2) + (cch << 4)) = pkd;
  }

  // consumer: A-fragments for tap 0 / cc 0 (4 m-tiles), prefetched, named
  f16x8 a0, a1, a2, a3;
  if (!prod) {
    a0 = af_load(0, 0); a1 = af_load(0, 1);
    a2 = af_load(0, 2); a3 = af_load(0, 3);
  }
  __syncthreads();

#pragma unroll 1
  for (int kk = 0; kk < 9; ++kk) {
    if (prod) {
      // ---- producer: build tap kk+1 into the other buffer (r5 loop, 16 tasks) ----
      if (kk < 8) {
        char* Bw = (char*)&Bs[(kk & 1) ^ 1][0];
        int base = (kk + 1) << 7;
        uint2 wA = swl[base + ph];
        ushort4 pvA = sol[base + ph];
        uint4 A0 = *(const uint4*)(bchp + ((int)pvA.x << 9));
        uint4 A1 = *(const uint4*)(bchp + ((int)pvA.y << 9));
        uint4 A2 = *(const uint4*)(bchp + ((int)pvA.z << 9));
        uint4 A3 = *(const uint4*)(bchp + ((int)pvA.w << 9));
#pragma unroll
        for (int s = 0; s < 16; ++s) {
          uint4 B0, B1, B2, B3; uint2 wB;
          if (s < 15) {   // depth-1 prefetch: issue next px's gathers first
            ushort4 pv = sol[base + ((s + 1) << 3) + ph];
            wB = swl[base + ((s + 1) << 3) + ph];
            B0 = *(const uint4*)(bchp + ((int)pv.x << 9));
            B1 = *(const uint4*)(bchp + ((int)pv.y << 9));
            B2 = *(const uint4*)(bchp + ((int)pv.z << 9));
            B3 = *(const uint4*)(bchp + ((int)pv.w << 9));
          }
          {
            HU ha, hb; ha.u = wA.x; hb.u = wA.y;
            float s0=0.f,s1=0.f,s2=0.f,s3=0.f,s4=0.f,s5=0.f,s6=0.f,s7=0.f;
            CMB(A0, (float)ha.h.x);
            CMB(A1, (float)ha.h.y);
            CMB(A2, (float)hb.h.x);
            CMB(A3, (float)hb.h.y);
            uint4 pkd;
            pkd.x = pkh(s0, s1); pkd.y = pkh(s2, s3);
            pkd.z = pkh(s4, s5); pkd.w = pkh(s6, s7);
            *(uint4*)(Bw + ((s << 3) + ph) * (BSTR * 2) + (ch << 4)) = pkd;
          }
          wA = wB; A0 = B0; A1 = B1; A2 = B2; A3 = B3;  // SSA rotate (unrolled)
        }
      }
    } else {
      // ---- consumer: 64Cout x 64px over Bs[kk&1]; af dbuf one cc ahead ----
      const char* Br = (const char*)&Bs[kk & 1][0];
      int fbase = kk << 3;
#pragma unroll
      for (int cc = 0; cc < 8; ++cc) {
        f16x8 b0 = bf_load(Br, 0, cc);
        f16x8 b1 = bf_load(Br, 1, cc);
        f16x8 b2 = bf_load(Br, 2, cc);
        f16x8 b3 = bf_load(Br, 3, cc);
        f16x8 n0, n1, n2, n3;
        if (cc < 7) {
          n0 = af_load(fbase + cc + 1, 0); n1 = af_load(fbase + cc + 1, 1);
          n2 = af_load(fbase + cc + 1, 2); n3 = af_load(fbase + cc + 1, 3);
        } else if (kk < 8) {
          n0 = af_load(fbase + 8, 0); n1 = af_load(fbase + 8, 1);
          n2 = af_load(fbase + 8, 2); n3 = af_load(fbase + 8, 3);
        }
        __builtin_amdgcn_s_setprio(1);
        acc[0][0] = __builtin_amdgcn_mfma_f32_16x16x32_f16(a0, b0, acc[0][0], 0, 0, 0);
        acc[0][1] = __builtin_amdgcn_mfma_f32_16x16x32_f16(a0, b1, acc[0][1], 0, 0, 0);
        acc[0][2] = __builtin_amdgcn_mfma_f32_16x16x32_f16(a0, b2, acc[0][2], 0, 0, 0);
        acc[0][3] = __builtin_amdgcn_mfma_f32_16x16x32_f16(a0, b3, acc[0][3], 0, 0, 0);
        acc[1][0] = __builtin_amdgcn_mfma_f32_16x16x32_f16(a1, b0, acc[1][0], 0, 0, 0);
        acc[1][1] = __builtin_amdgcn_mfma_f32_16x16x32_f16(a1, b1, acc[1][1], 0, 0, 0);
        acc[1][2] = __builtin_amdgcn_mfma_f32_16x16x32_f16(a1, b2, acc[1][2], 0, 0, 0);
        acc[1][3] = __builtin_amdgcn_mfma_f32_16x16x32_f16(a1, b3, acc[1][3], 0, 0, 0);
        acc[2][0] = __builtin_amdgcn_mfma_f32_16x16x32_f16(a2, b0, acc[2][0], 0, 0, 0);
        acc[2][1] = __builtin_amdgcn_mfma_f32_16x16x32_f16(a2, b1, acc[2][1], 0, 0, 0);
        acc[2][2] = __builtin_amdgcn_mfma_f32_16x16x32_f16(a2, b2, acc[2][2], 0, 0, 0);
        acc[2][3] = __builtin_amdgcn_mfma_f32_16x16x32_f16(a2, b3, acc[2][3], 0, 0, 0);
        acc[3][0] = __builtin_amdgcn_mfma_f32_16x16x32_f16(a3, b0, acc[3][0], 0, 0, 0);
        acc[3][1] = __builtin_amdgcn_mfma_f32_16x16x32_f16(a3, b1, acc[3][1], 0, 0, 0);
        acc[3][2] = __builtin_amdgcn_mfma_f32_16x16x32_f16(a3, b2, acc[3][2], 0, 0, 0);
        acc[3][3] = __builtin_amdgcn_mfma_f32_16x16x32_f16(a3, b3, acc[3][3], 0, 0, 0);
        __builtin_amdgcn_s_setprio(0);
        a0 = n0; a1 = n1; a2 = n2; a3 = n3;   // SSA rotate (unrolled)
      }
    }
    __syncthreads();   // producers done writing Bs[cur^1]; consumers done reading Bs[cur]
  }

  // epilogue: consumers hold complete sums -- direct store, no LDS reduce
  if (!prod) {
    // D layout: row = q*4+r (Cout), col = ml (px); m91-verified
    size_t ob = (size_t)n * COUT * HW + ((size_t)hp << 7);
#pragma unroll
    for (int mt = 0; mt < 4; ++mt) {
      int co0 = (coT << 6) + (mt << 4) + (q << 2);
      f4u bv = *(const f4u*)&bias[co0];
#pragma unroll
      for (int nt = 0; nt < 4; ++nt) {
        int px = rbase + (nt << 4) + ml;
#pragma unroll
        for (int r = 0; r < 4; ++r)
          out[ob + (size_t)(co0 + r) * HW + px] = acc[mt][nt][r] + bv[r];
      }
    }
  }
}

extern "C" void kernel_launch(void* const* d_in, const int* in_sizes, int n_in,
                              void* d_out, int out_size, void* d_ws, size_t ws_size,
                              hipStream_t stream) {
  const float* x      = (const float*)d_in[0];
  const float* offset = (const float*)d_in[1];
  const float* mask   = (const float*)d_in[2];
  const float* weight = (const float*)d_in[3];
  const float* bias   = (const float*)d_in[4];
  float* out = (float*)d_out;

  u16* xT  = (u16*)d_ws;                                      // 16 MB fp16
  u16* W2f = (u16*)((char*)d_ws + (size_t)NB * HW * CIN * 2); // +1.18 MB fp16

  prep_all<<<2176, 256, 0, stream>>>(x, weight, (u32*)xT, (u32*)W2f);
  dcn_main<<<256, 768, 0, stream>>>(offset, mask, bias, xT, W2f, out);
}